// Round 6
// baseline (1733.907 us; speedup 1.0000x reference)
//
#include <hip/hip_runtime.h>
#include <math.h>

// InstantNGP fused forward: contraction + hashgrid(16 lvl, F=2) + SH9 + MLP 41->64->64->4
// One thread per point, fp32. Layer-0 fused into the encode (its FMAs hide gather
// latency); levels software-pipelined 2-deep (16 gathers in flight).
// Levels 0..3 dense (17^3,26^3,42^3,67^3 <= 2^19), 4..15 hashed.
// Pipeline order: hashed levels FIRST (long-latency L3 gathers issued early,
// covered by SH+ACC work), dense L2-resident levels LAST (short tail stall).
// __launch_bounds__(256,4): cap at 128 VGPR -> 16 waves/CU -> ~256 outstanding lines/CU.

#define TSIZE (1u << 19)

// Issue the 8 corner gathers for level `l` into buffer `b`.
#define NGP_LOAD(l, b) do {                                                   \
    const int res = RES_[(l)];                                                \
    const bool dense = ((l) < 4);  /* compile-time; avoids int32 overflow */  \
    float xx = px * (float)res, yy = py * (float)res, zz = pz * (float)res;   \
    unsigned xi = (unsigned)floorf(xx), yi = (unsigned)floorf(yy),            \
             zi = (unsigned)floorf(zz);                                       \
    const float2* tl = (const float2*)tab + (size_t)(l) * TSIZE;              \
    unsigned tx0, tx1, ty0, ty1, tz0, tz1;                                    \
    if (dense) {                                                              \
        const unsigned r1 = (unsigned)(res + 1);                              \
        tx0 = xi;           tx1 = xi + 1u;                                    \
        ty0 = yi * r1;      ty1 = ty0 + r1;                                   \
        tz0 = zi * (r1*r1); tz1 = tz0 + (r1*r1);                              \
    } else {                                                                  \
        tx0 = xi;               tx1 = xi + 1u;                                \
        ty0 = yi * 2654435761u; ty1 = ty0 + 2654435761u;                      \
        tz0 = zi * 805459861u;  tz1 = tz0 + 805459861u;                       \
    }                                                                         \
    _Pragma("unroll")                                                         \
    for (int c = 0; c < 8; c++) {                                             \
        unsigned tx = (c & 1) ? tx1 : tx0;                                    \
        unsigned ty = (c & 2) ? ty1 : ty0;                                    \
        unsigned tz = (c & 4) ? tz1 : tz0;                                    \
        unsigned idx = dense ? (tx + ty + tz)                                 \
                             : ((tx ^ ty ^ tz) & (TSIZE - 1u));               \
        v[b][c] = tl[idx];                                                    \
    }                                                                         \
} while (0)

// Trilinear-combine buffer `b` (level `l`), FMA into h via W0 rows 2l, 2l+1.
// Fractional weights recomputed from the live contracted position (saves VGPRs).
#define NGP_ACC(l, b) do {                                                    \
    const int res = RES_[(l)];                                                \
    float xx = px * (float)res, yy = py * (float)res, zz = pz * (float)res;   \
    float wx1 = xx - floorf(xx), wy1 = yy - floorf(yy), wz1 = zz - floorf(zz);\
    float wx0 = 1.0f - wx1, wy0 = 1.0f - wy1, wz0 = 1.0f - wz1;               \
    float f0 = 0.0f, f1 = 0.0f;                                               \
    _Pragma("unroll")                                                         \
    for (int c = 0; c < 8; c++) {                                             \
        float wgt = ((c & 1) ? wx1 : wx0) * ((c & 2) ? wy1 : wy0)             \
                  * ((c & 4) ? wz1 : wz0);                                    \
        f0 = fmaf(wgt, v[b][c].x, f0);                                        \
        f1 = fmaf(wgt, v[b][c].y, f1);                                        \
    }                                                                         \
    _Pragma("unroll")                                                         \
    for (int j = 0; j < 64; j++) {                                            \
        h[j] = fmaf(f1, W0[(2*(l)+1)*64 + j], fmaf(f0, W0[(2*(l))*64 + j], h[j])); \
    }                                                                         \
} while (0)

__global__ __launch_bounds__(256, 4) void ngp_fwd(
                        const float* __restrict__ pos,
                        const float* __restrict__ dirs,
                        const float* __restrict__ tab,
                        const float* __restrict__ W0,
                        const float* __restrict__ W1,
                        const float* __restrict__ W2,
                        float* __restrict__ out,
                        int N)
{
    int n = blockIdx.x * blockDim.x + threadIdx.x;
    if (n >= N) return;

    const int RES_[16] = {16,25,41,66,107,173,279,450,725,1169,1883,3035,4889,7877,12689,20443};

    // ---- inputs: issue both loads up front; contraction math covers dirs latency ----
    float px = pos[3*n+0], py = pos[3*n+1], pz = pos[3*n+2];
    float dx_ = dirs[3*n+0], dy_ = dirs[3*n+1], dz_ = dirs[3*n+2];

    // ---- cube scene contraction (matches reference op order) ----
    {
        float ax = fabsf(px), ay = fabsf(py), az = fabsf(pz);
        float m = fmaxf(ax, fmaxf(ay, az));
        float major = (ax >= ay && ax >= az) ? px : ((ay >= az) ? py : pz);
        bool inner = (m <= 4.0f);
        float sm = inner ? 1.0f : major;
        float nm = (sm > 0.0f) ? (2.0f - 4.0f / sm) : (-2.0f - 4.0f / sm);
        float ratio = nm / sm;
        float s = inner ? 0.25f : ratio;       // p/A == p*0.25
        px = (px * s + 2.0f) * 0.25f;          // (model+2)/4
        py = (py * s + 2.0f) * 0.25f;
        pz = (pz * s + 2.0f) * 0.25f;
    }

    float2 v[2][8];     // double-buffered corner values (statically indexed)
    float  h[64];       // layer-0 accumulator

    // Kick off the first two hashed levels' gathers (16 L3-bound loads in flight)...
    NGP_LOAD(4, 0);
    NGP_LOAD(5, 1);

    // ...cover their latency with the SH portion of layer 0 (rows 32..40: 576 FMAs).
    {
        float s1 = -0.4886025119029199f * dy_;
        float s2 =  0.4886025119029199f * dz_;
        float s3 = -0.4886025119029199f * dx_;
        float s4 =  1.0925484305920792f * dx_ * dy_;
        float s5 = -1.0925484305920792f * dy_ * dz_;
        float s6 =  0.31539156525252005f * (2.0f*dz_*dz_ - dx_*dx_ - dy_*dy_);
        float s7 = -1.0925484305920792f * dx_ * dz_;
        float s8 =  0.5462742152960396f * (dx_*dx_ - dy_*dy_);
        #pragma unroll
        for (int j = 0; j < 64; j++) {
            float a = 0.28209479177387814f * W0[32*64 + j];
            a = fmaf(s1, W0[33*64 + j], a);
            a = fmaf(s2, W0[34*64 + j], a);
            a = fmaf(s3, W0[35*64 + j], a);
            a = fmaf(s4, W0[36*64 + j], a);
            a = fmaf(s5, W0[37*64 + j], a);
            a = fmaf(s6, W0[38*64 + j], a);
            a = fmaf(s7, W0[39*64 + j], a);
            a = fmaf(s8, W0[40*64 + j], a);
            h[j] = a;
        }
    }

    // 2-deep pipelined encode + fused layer 0. Hashed 4..15 first, dense 0..3 last.
    NGP_ACC(4, 0);   NGP_LOAD(6, 0);
    NGP_ACC(5, 1);   NGP_LOAD(7, 1);
    NGP_ACC(6, 0);   NGP_LOAD(8, 0);
    NGP_ACC(7, 1);   NGP_LOAD(9, 1);
    NGP_ACC(8, 0);   NGP_LOAD(10, 0);
    NGP_ACC(9, 1);   NGP_LOAD(11, 1);
    NGP_ACC(10, 0);  NGP_LOAD(12, 0);
    NGP_ACC(11, 1);  NGP_LOAD(13, 1);
    NGP_ACC(12, 0);  NGP_LOAD(14, 0);
    NGP_ACC(13, 1);  NGP_LOAD(15, 1);
    NGP_ACC(14, 0);  NGP_LOAD(0, 0);
    NGP_ACC(15, 1);  NGP_LOAD(1, 1);
    NGP_ACC(0, 0);   NGP_LOAD(2, 0);
    NGP_ACC(1, 1);   NGP_LOAD(3, 1);
    NGP_ACC(2, 0);
    NGP_ACC(3, 1);

    // ---- relu after layer 0 ----
    #pragma unroll
    for (int j = 0; j < 64; j++) h[j] = fmaxf(h[j], 0.0f);

    // ---- layers 1+2 fused in 16-wide tiles (caps live VGPRs) ----
    float o0 = 0.0f, o1 = 0.0f, o2 = 0.0f, o3 = 0.0f;
    #pragma unroll
    for (int jt = 0; jt < 4; jt++) {
        float h2[16];
        #pragma unroll
        for (int j = 0; j < 16; j++) h2[j] = 0.0f;
        #pragma unroll
        for (int i = 0; i < 64; i++) {
            const float e = h[i];
            #pragma unroll
            for (int j = 0; j < 16; j++) h2[j] = fmaf(e, W1[i*64 + jt*16 + j], h2[j]);
        }
        #pragma unroll
        for (int j = 0; j < 16; j++) {
            float val = fmaxf(h2[j], 0.0f);
            o0 = fmaf(val, W2[(jt*16 + j)*4 + 0], o0);
            o1 = fmaf(val, W2[(jt*16 + j)*4 + 1], o1);
            o2 = fmaf(val, W2[(jt*16 + j)*4 + 2], o2);
            o3 = fmaf(val, W2[(jt*16 + j)*4 + 3], o3);
        }
    }

    // ---- head: density + rgb ----
    float density = fminf(expf(o0), fmaxf(o0, 0.0f) + 1000000.0f);
    float r = 1.0f / (1.0f + expf(-o1));
    float g = 1.0f / (1.0f + expf(-o2));
    float b = 1.0f / (1.0f + expf(-o3));

    *reinterpret_cast<float4*>(out + 4*(size_t)n) = make_float4(density, r, g, b);
}

extern "C" void kernel_launch(void* const* d_in, const int* in_sizes, int n_in,
                              void* d_out, int out_size, void* d_ws, size_t ws_size,
                              hipStream_t stream) {
    const float* pos = (const float*)d_in[0];
    const float* dir = (const float*)d_in[1];
    const float* tab = (const float*)d_in[2];
    const float* W0  = (const float*)d_in[3];
    const float* W1  = (const float*)d_in[4];
    const float* W2  = (const float*)d_in[5];
    float* out = (float*)d_out;

    int N = in_sizes[0] / 3;
    dim3 block(256);
    dim3 grid((N + 255) / 256);
    hipLaunchKernelGGL(ngp_fwd, grid, block, 0, stream, pos, dir, tab, W0, W1, W2, out, N);
}

// Round 9
// 1427.736 us; speedup vs baseline: 1.2144x; 1.2144x over previous
//
#include <hip/hip_runtime.h>
#include <hip/hip_fp16.h>
#include <math.h>

// InstantNGP forward, level-blocked ("split") schedule v3:
//   cvt_tab:     fp32 table -> fp16 (half2/entry) in d_ws
//   contract_k:  contraction once -> cpos float3; ALSO does dense levels 0..3
//                (3.2 MiB fp32 slab, L2-resident) -> feats half2
//   enc_hash:    one pass per hashed level 4..15 (2 MiB fp16 slab L2-resident)
//   mlp_k:       feats(16xhalf2) + SH -> 41->64->64->4 + head
// R6 profile: fused kernel L2-miss-bound (FETCH 5.9 GB @3.55 TB/s, VALUBusy 28%).
// Level-blocking turns ~244 touches/line into L2 hits -> traffic ~= cold fill.
// Fallback: if ws_size < needed, run R6 fused kernel (passed, absmax 0.0078).

#define TSIZE (1u << 19)
#define P1H 2654435761u
#define P2H 805459861u

__device__ __forceinline__ void contract_pt(float& px, float& py, float& pz) {
    float ax = fabsf(px), ay = fabsf(py), az = fabsf(pz);
    float m = fmaxf(ax, fmaxf(ay, az));
    float major = (ax >= ay && ax >= az) ? px : ((ay >= az) ? py : pz);
    bool inner = (m <= 4.0f);
    float sm = inner ? 1.0f : major;
    float nm = (sm > 0.0f) ? (2.0f - 4.0f / sm) : (-2.0f - 4.0f / sm);
    float ratio = nm / sm;
    float s = inner ? 0.25f : ratio;       // p/A == p*0.25
    px = (px * s + 2.0f) * 0.25f;          // (model+2)/4
    py = (py * s + 2.0f) * 0.25f;
    pz = (pz * s + 2.0f) * 0.25f;
}

// ---------------- split-path kernels ----------------

__global__ __launch_bounds__(256) void cvt_tab(const float2* __restrict__ tab,
                                               __half2* __restrict__ htab, int ntot)
{
    int i = blockIdx.x * blockDim.x + threadIdx.x;
    if (i < ntot) {
        float2 v = tab[i];
        htab[i] = __floats2half2_rn(v.x, v.y);
    }
}

// Contraction -> cpos (packed float3), plus dense levels 0..3 -> feats.
__global__ __launch_bounds__(256) void contract_k(const float* __restrict__ pos,
                                                  const float* __restrict__ tab,
                                                  float* __restrict__ cpos,
                                                  __half2* __restrict__ feats, int N)
{
    int n = blockIdx.x * blockDim.x + threadIdx.x;
    if (n >= N) return;
    float px = pos[3*n+0], py = pos[3*n+1], pz = pos[3*n+2];
    contract_pt(px, py, pz);
    cpos[3*n+0] = px; cpos[3*n+1] = py; cpos[3*n+2] = pz;

    const int RES_[4] = {16, 25, 41, 66};
    #pragma unroll
    for (int l = 0; l < 4; l++) {
        const int res = RES_[l];
        const unsigned r1 = (unsigned)(res + 1);
        float xx = px * (float)res, yy = py * (float)res, zz = pz * (float)res;
        float xf = floorf(xx), yf = floorf(yy), zf = floorf(zz);
        float wx1 = xx - xf, wy1 = yy - yf, wz1 = zz - zf;
        float wx0 = 1.0f - wx1, wy0 = 1.0f - wy1, wz0 = 1.0f - wz1;
        unsigned xi = (unsigned)xf, yi = (unsigned)yf, zi = (unsigned)zf;
        const float2* tl = (const float2*)tab + (size_t)l * TSIZE;
        unsigned ty0 = yi * r1, tz0 = zi * (r1 * r1);

        float2 v[8];
        #pragma unroll
        for (int c = 0; c < 8; c++) {
            unsigned idx = (xi + ((c & 1) ? 1u : 0u))
                         + (ty0 + ((c & 2) ? r1 : 0u))
                         + (tz0 + ((c & 4) ? r1 * r1 : 0u));
            v[c] = tl[idx];
        }
        float f0 = 0.0f, f1 = 0.0f;
        #pragma unroll
        for (int c = 0; c < 8; c++) {
            float wgt = ((c & 1) ? wx1 : wx0) * ((c & 2) ? wy1 : wy0)
                      * ((c & 4) ? wz1 : wz0);
            f0 = fmaf(wgt, v[c].x, f0);
            f1 = fmaf(wgt, v[c].y, f1);
        }
        feats[(size_t)l * N + n] = __floats2half2_rn(f0, f1);
    }
}

// One hashed level per pass: fp16 slab (2 MiB) stays L2-resident for the pass.
__global__ __launch_bounds__(256) void enc_hash(const float* __restrict__ cpos,
                                                const __half2* __restrict__ htab,
                                                __half2* __restrict__ feats,
                                                int level, int res, int N)
{
    int n = blockIdx.x * blockDim.x + threadIdx.x;
    if (n >= N) return;
    float px = cpos[3*n+0], py = cpos[3*n+1], pz = cpos[3*n+2];

    float xx = px * (float)res, yy = py * (float)res, zz = pz * (float)res;
    float xf = floorf(xx), yf = floorf(yy), zf = floorf(zz);
    float wx1 = xx - xf, wy1 = yy - yf, wz1 = zz - zf;
    float wx0 = 1.0f - wx1, wy0 = 1.0f - wy1, wz0 = 1.0f - wz1;
    unsigned xi = (unsigned)xf, yi = (unsigned)yf, zi = (unsigned)zf;
    const __half2* tl = htab + (size_t)level * TSIZE;
    unsigned ty0 = yi * P1H, tz0 = zi * P2H;

    __half2 v[8];
    #pragma unroll
    for (int c = 0; c < 8; c++) {
        unsigned tx = xi + ((c & 1) ? 1u : 0u);
        unsigned ty = ty0 + ((c & 2) ? P1H : 0u);
        unsigned tz = tz0 + ((c & 4) ? P2H : 0u);
        unsigned idx = (tx ^ ty ^ tz) & (TSIZE - 1u);
        v[c] = tl[idx];
    }
    float f0 = 0.0f, f1 = 0.0f;
    #pragma unroll
    for (int c = 0; c < 8; c++) {
        float2 vv = __half22float2(v[c]);
        float wgt = ((c & 1) ? wx1 : wx0) * ((c & 2) ? wy1 : wy0)
                  * ((c & 4) ? wz1 : wz0);
        f0 = fmaf(wgt, vv.x, f0);
        f1 = fmaf(wgt, vv.y, f1);
    }
    feats[(size_t)level * N + n] = __floats2half2_rn(f0, f1);
}

// Final MLP: pure streaming + VALU (no table access).
__global__ __launch_bounds__(256, 4) void mlp_k(const float* __restrict__ dirs,
                                                const __half2* __restrict__ feats,
                                                const float* __restrict__ W0,
                                                const float* __restrict__ W1,
                                                const float* __restrict__ W2,
                                                float* __restrict__ out, int N)
{
    int n = blockIdx.x * blockDim.x + threadIdx.x;
    if (n >= N) return;

    // Issue all 16 feature loads up front (16 coalesced streams in flight).
    __half2 f[16];
    #pragma unroll
    for (int l = 0; l < 16; l++) f[l] = feats[(size_t)l * N + n];
    float dx_ = dirs[3*n+0], dy_ = dirs[3*n+1], dz_ = dirs[3*n+2];

    float h[64];
    // SH rows 32..40 first (covers feature-load latency).
    {
        float s1 = -0.4886025119029199f * dy_;
        float s2 =  0.4886025119029199f * dz_;
        float s3 = -0.4886025119029199f * dx_;
        float s4 =  1.0925484305920792f * dx_ * dy_;
        float s5 = -1.0925484305920792f * dy_ * dz_;
        float s6 =  0.31539156525252005f * (2.0f*dz_*dz_ - dx_*dx_ - dy_*dy_);
        float s7 = -1.0925484305920792f * dx_ * dz_;
        float s8 =  0.5462742152960396f * (dx_*dx_ - dy_*dy_);
        #pragma unroll
        for (int j = 0; j < 64; j++) {
            float a = 0.28209479177387814f * W0[32*64 + j];
            a = fmaf(s1, W0[33*64 + j], a);
            a = fmaf(s2, W0[34*64 + j], a);
            a = fmaf(s3, W0[35*64 + j], a);
            a = fmaf(s4, W0[36*64 + j], a);
            a = fmaf(s5, W0[37*64 + j], a);
            a = fmaf(s6, W0[38*64 + j], a);
            a = fmaf(s7, W0[39*64 + j], a);
            a = fmaf(s8, W0[40*64 + j], a);
            h[j] = a;
        }
    }
    #pragma unroll
    for (int l = 0; l < 16; l++) {
        float2 fv = __half22float2(f[l]);
        #pragma unroll
        for (int j = 0; j < 64; j++)
            h[j] = fmaf(fv.y, W0[(2*l+1)*64 + j], fmaf(fv.x, W0[(2*l)*64 + j], h[j]));
    }
    #pragma unroll
    for (int j = 0; j < 64; j++) h[j] = fmaxf(h[j], 0.0f);

    float o0 = 0.0f, o1 = 0.0f, o2 = 0.0f, o3 = 0.0f;
    #pragma unroll
    for (int jt = 0; jt < 4; jt++) {
        float h2[16];
        #pragma unroll
        for (int j = 0; j < 16; j++) h2[j] = 0.0f;
        #pragma unroll
        for (int i = 0; i < 64; i++) {
            const float e = h[i];
            #pragma unroll
            for (int j = 0; j < 16; j++) h2[j] = fmaf(e, W1[i*64 + jt*16 + j], h2[j]);
        }
        #pragma unroll
        for (int j = 0; j < 16; j++) {
            float val = fmaxf(h2[j], 0.0f);
            o0 = fmaf(val, W2[(jt*16 + j)*4 + 0], o0);
            o1 = fmaf(val, W2[(jt*16 + j)*4 + 1], o1);
            o2 = fmaf(val, W2[(jt*16 + j)*4 + 2], o2);
            o3 = fmaf(val, W2[(jt*16 + j)*4 + 3], o3);
        }
    }

    float density = fminf(expf(o0), fmaxf(o0, 0.0f) + 1000000.0f);
    float r = 1.0f / (1.0f + expf(-o1));
    float g = 1.0f / (1.0f + expf(-o2));
    float b = 1.0f / (1.0f + expf(-o3));
    *reinterpret_cast<float4*>(out + 4*(size_t)n) = make_float4(density, r, g, b);
}

// ---------------- fallback: R6 fused kernel (passed; unchanged) ----------------

#define NGP_LOAD(l, b) do {                                                   \
    const int res = RES_[(l)];                                                \
    const bool dense = ((l) < 4);                                             \
    float xx = px * (float)res, yy = py * (float)res, zz = pz * (float)res;   \
    unsigned xi = (unsigned)floorf(xx), yi = (unsigned)floorf(yy),            \
             zi = (unsigned)floorf(zz);                                       \
    const float2* tl = (const float2*)tab + (size_t)(l) * TSIZE;              \
    unsigned tx0, tx1, ty0, ty1, tz0, tz1;                                    \
    if (dense) {                                                              \
        const unsigned r1 = (unsigned)(res + 1);                              \
        tx0 = xi;           tx1 = xi + 1u;                                    \
        ty0 = yi * r1;      ty1 = ty0 + r1;                                   \
        tz0 = zi * (r1*r1); tz1 = tz0 + (r1*r1);                              \
    } else {                                                                  \
        tx0 = xi;               tx1 = xi + 1u;                                \
        ty0 = yi * P1H;         ty1 = ty0 + P1H;                              \
        tz0 = zi * P2H;         tz1 = tz0 + P2H;                              \
    }                                                                         \
    _Pragma("unroll")                                                         \
    for (int c = 0; c < 8; c++) {                                             \
        unsigned tx = (c & 1) ? tx1 : tx0;                                    \
        unsigned ty = (c & 2) ? ty1 : ty0;                                    \
        unsigned tz = (c & 4) ? tz1 : tz0;                                    \
        unsigned idx = dense ? (tx + ty + tz)                                 \
                             : ((tx ^ ty ^ tz) & (TSIZE - 1u));               \
        v[b][c] = tl[idx];                                                    \
    }                                                                         \
} while (0)

#define NGP_ACC(l, b) do {                                                    \
    const int res = RES_[(l)];                                                \
    float xx = px * (float)res, yy = py * (float)res, zz = pz * (float)res;   \
    float wx1 = xx - floorf(xx), wy1 = yy - floorf(yy), wz1 = zz - floorf(zz);\
    float wx0 = 1.0f - wx1, wy0 = 1.0f - wy1, wz0 = 1.0f - wz1;               \
    float f0 = 0.0f, f1 = 0.0f;                                               \
    _Pragma("unroll")                                                         \
    for (int c = 0; c < 8; c++) {                                             \
        float wgt = ((c & 1) ? wx1 : wx0) * ((c & 2) ? wy1 : wy0)             \
                  * ((c & 4) ? wz1 : wz0);                                    \
        f0 = fmaf(wgt, v[b][c].x, f0);                                        \
        f1 = fmaf(wgt, v[b][c].y, f1);                                        \
    }                                                                         \
    _Pragma("unroll")                                                         \
    for (int j = 0; j < 64; j++) {                                            \
        h[j] = fmaf(f1, W0[(2*(l)+1)*64 + j], fmaf(f0, W0[(2*(l))*64 + j], h[j])); \
    }                                                                         \
} while (0)

__global__ __launch_bounds__(256, 4) void ngp_fwd(
                        const float* __restrict__ pos,
                        const float* __restrict__ dirs,
                        const float* __restrict__ tab,
                        const float* __restrict__ W0,
                        const float* __restrict__ W1,
                        const float* __restrict__ W2,
                        float* __restrict__ out,
                        int N)
{
    int n = blockIdx.x * blockDim.x + threadIdx.x;
    if (n >= N) return;
    const int RES_[16] = {16,25,41,66,107,173,279,450,725,1169,1883,3035,4889,7877,12689,20443};
    float px = pos[3*n+0], py = pos[3*n+1], pz = pos[3*n+2];
    float dx_ = dirs[3*n+0], dy_ = dirs[3*n+1], dz_ = dirs[3*n+2];
    contract_pt(px, py, pz);

    float2 v[2][8];
    float  h[64];
    NGP_LOAD(4, 0);
    NGP_LOAD(5, 1);
    {
        float s1 = -0.4886025119029199f * dy_;
        float s2 =  0.4886025119029199f * dz_;
        float s3 = -0.4886025119029199f * dx_;
        float s4 =  1.0925484305920792f * dx_ * dy_;
        float s5 = -1.0925484305920792f * dy_ * dz_;
        float s6 =  0.31539156525252005f * (2.0f*dz_*dz_ - dx_*dx_ - dy_*dy_);
        float s7 = -1.0925484305920792f * dx_ * dz_;
        float s8 =  0.5462742152960396f * (dx_*dx_ - dy_*dy_);
        #pragma unroll
        for (int j = 0; j < 64; j++) {
            float a = 0.28209479177387814f * W0[32*64 + j];
            a = fmaf(s1, W0[33*64 + j], a);
            a = fmaf(s2, W0[34*64 + j], a);
            a = fmaf(s3, W0[35*64 + j], a);
            a = fmaf(s4, W0[36*64 + j], a);
            a = fmaf(s5, W0[37*64 + j], a);
            a = fmaf(s6, W0[38*64 + j], a);
            a = fmaf(s7, W0[39*64 + j], a);
            a = fmaf(s8, W0[40*64 + j], a);
            h[j] = a;
        }
    }
    NGP_ACC(4, 0);   NGP_LOAD(6, 0);
    NGP_ACC(5, 1);   NGP_LOAD(7, 1);
    NGP_ACC(6, 0);   NGP_LOAD(8, 0);
    NGP_ACC(7, 1);   NGP_LOAD(9, 1);
    NGP_ACC(8, 0);   NGP_LOAD(10, 0);
    NGP_ACC(9, 1);   NGP_LOAD(11, 1);
    NGP_ACC(10, 0);  NGP_LOAD(12, 0);
    NGP_ACC(11, 1);  NGP_LOAD(13, 1);
    NGP_ACC(12, 0);  NGP_LOAD(14, 0);
    NGP_ACC(13, 1);  NGP_LOAD(15, 1);
    NGP_ACC(14, 0);  NGP_LOAD(0, 0);
    NGP_ACC(15, 1);  NGP_LOAD(1, 1);
    NGP_ACC(0, 0);   NGP_LOAD(2, 0);
    NGP_ACC(1, 1);   NGP_LOAD(3, 1);
    NGP_ACC(2, 0);
    NGP_ACC(3, 1);

    #pragma unroll
    for (int j = 0; j < 64; j++) h[j] = fmaxf(h[j], 0.0f);

    float o0 = 0.0f, o1 = 0.0f, o2 = 0.0f, o3 = 0.0f;
    #pragma unroll
    for (int jt = 0; jt < 4; jt++) {
        float h2[16];
        #pragma unroll
        for (int j = 0; j < 16; j++) h2[j] = 0.0f;
        #pragma unroll
        for (int i = 0; i < 64; i++) {
            const float e = h[i];
            #pragma unroll
            for (int j = 0; j < 16; j++) h2[j] = fmaf(e, W1[i*64 + jt*16 + j], h2[j]);
        }
        #pragma unroll
        for (int j = 0; j < 16; j++) {
            float val = fmaxf(h2[j], 0.0f);
            o0 = fmaf(val, W2[(jt*16 + j)*4 + 0], o0);
            o1 = fmaf(val, W2[(jt*16 + j)*4 + 1], o1);
            o2 = fmaf(val, W2[(jt*16 + j)*4 + 2], o2);
            o3 = fmaf(val, W2[(jt*16 + j)*4 + 3], o3);
        }
    }

    float density = fminf(expf(o0), fmaxf(o0, 0.0f) + 1000000.0f);
    float r = 1.0f / (1.0f + expf(-o1));
    float g = 1.0f / (1.0f + expf(-o2));
    float b = 1.0f / (1.0f + expf(-o3));
    *reinterpret_cast<float4*>(out + 4*(size_t)n) = make_float4(density, r, g, b);
}

// ---------------- launcher ----------------

extern "C" void kernel_launch(void* const* d_in, const int* in_sizes, int n_in,
                              void* d_out, int out_size, void* d_ws, size_t ws_size,
                              hipStream_t stream) {
    const float* pos = (const float*)d_in[0];
    const float* dir = (const float*)d_in[1];
    const float* tab = (const float*)d_in[2];
    const float* W0  = (const float*)d_in[3];
    const float* W1  = (const float*)d_in[4];
    const float* W2  = (const float*)d_in[5];
    float* out = (float*)d_out;

    const int N = in_sizes[0] / 3;
    const int RES_H[16] = {16,25,41,66,107,173,279,450,725,1169,1883,3035,4889,7877,12689,20443};

    const size_t htab_bytes  = (size_t)16 * TSIZE * 4;   // half2 per entry: 32 MB
    const size_t cpos_bytes  = (size_t)N * 12;           // packed float3: 24 MB
    const size_t feats_bytes = (size_t)16 * N * 4;       // half2 per level: 134 MB
    const size_t need = htab_bytes + cpos_bytes + feats_bytes;

    dim3 block(256);
    dim3 gridN((N + 255) / 256);

    if (ws_size >= need) {
        __half2* htab  = (__half2*)d_ws;
        float*   cpos  = (float*)((char*)d_ws + htab_bytes);
        __half2* feats = (__half2*)((char*)d_ws + htab_bytes + cpos_bytes);

        const int ntot = 16 * (int)TSIZE;
        hipLaunchKernelGGL(cvt_tab, dim3((ntot + 255) / 256), block, 0, stream,
                           (const float2*)tab, htab, ntot);
        hipLaunchKernelGGL(contract_k, gridN, block, 0, stream, pos, tab, cpos, feats, N);
        for (int l = 4; l < 16; l++)
            hipLaunchKernelGGL(enc_hash, gridN, block, 0, stream,
                               cpos, htab, feats, l, RES_H[l], N);
        hipLaunchKernelGGL(mlp_k, gridN, block, 0, stream,
                           dir, feats, W0, W1, W2, out, N);
    } else {
        hipLaunchKernelGGL(ngp_fwd, gridN, block, 0, stream,
                           pos, dir, tab, W0, W1, W2, out, N);
    }
}